// Round 11
// baseline (397.602 us; speedup 1.0000x reference)
//
#include <hip/hip_runtime.h>
#include <math.h>

// DN test-mode forward, filter+rescore:
//  1) convert x -> f16 fragment-linear tiles (A staged via global_load_lds)
//  2) f16 MFMA GEMM, 256x256 tile, BK=32, 2 phases/tile, 2-deep W prefetch with
//     COUNTED vmcnt (never drains; T4) + fused ||w_y|| + row max + LDS-buffered append
//  3) global approx max per batch; 4) exact f32 rescore of survivors -> atomicMax
//  5) gather out[b,z] = y2z[z,winner]/||y2z[z,:]||

typedef _Float16 half8 __attribute__((ext_vector_type(8)));
typedef __attribute__((ext_vector_type(16))) float f32x16;
typedef unsigned long long ull;

#define TAU 0.006f
#define CAP 1572864u
#define LCAP 1024u

__device__ __forceinline__ unsigned pk2h(float a, float b) {
    union { _Float16 h; unsigned short u; } ca, cb;
    ca.h = (_Float16)a; cb.h = (_Float16)b;   // RNE
    return (unsigned)ca.u | ((unsigned)cb.u << 16);
}

// monotone-float key, smaller y wins ties
__device__ __forceinline__ ull packkey(float v, unsigned y) {
    unsigned m = __float_as_uint(v);
    m = (v >= 0.f) ? (m | 0x80000000u) : ~m;
    return ((ull)m << 32) | (ull)(0x7FFFFFFFu - y);
}

#define GLDS(gp, lp) __builtin_amdgcn_global_load_lds( \
    (const __attribute__((address_space(1))) void*)(gp), \
    (__attribute__((address_space(3))) void*)(lp), 16, 0, 0)

__global__ __launch_bounds__(512) void init_ctrl(const int* __restrict__ age,
                                                 ull* __restrict__ win,
                                                 unsigned* __restrict__ cnt) {
    const int t = threadIdx.x;
    int fi = 0x7fffffff;
    for (int y = t; y < 32768; y += 512)
        if (age[y] < 1) fi = min(fi, y);
    __shared__ int red[512];
    red[t] = fi;
    __syncthreads();
    for (int s = 256; s; s >>= 1) {
        if (t < s) red[t] = min(red[t], red[t + s]);
        __syncthreads();
    }
    const int f = red[0];
    const ull seed = (f < 32768) ? packkey(0.0f, (unsigned)f) : packkey(-1e30f, 0u);
    win[t] = seed;                      // t < 512 = B
    if (t == 0) *cnt = 0u;
}

// x -> f16, fragment-linear: o = (t*2+bx)*1024 + wm*256 + ks*128 + mi*64 + lane
__global__ __launch_bounds__(512) void convert_x(const float* __restrict__ x,
                                                 uint4* __restrict__ xf16) {
    const int o = blockIdx.x * 512 + threadIdx.x;   // 262144
    const int lane = o & 63;
    const int mi = (o >> 6) & 1;
    const int ks = (o >> 7) & 1;
    const int wm = (o >> 8) & 3;
    const int bx = (o >> 10) & 1;
    const int t  = o >> 11;
    const int row = (bx << 8) + (wm << 6) + (mi << 5) + (lane & 31);
    const int col = (t << 5) + (ks << 4) + ((lane >> 5) << 3);
    const float* src = x + (size_t)row * 4096 + col;
    const float4 a = *(const float4*)src;
    const float4 b = *(const float4*)(src + 4);
    uint4 u;
    u.x = pk2h(a.x, a.y); u.y = pk2h(a.z, a.w);
    u.z = pk2h(b.x, b.y); u.w = pk2h(b.z, b.w);
    xf16[o] = u;
}

__global__ __launch_bounds__(256) void row_norms(const float* __restrict__ src,
                                                 float* __restrict__ dst, int cols) {
    const int r = blockIdx.x;
    const float* row = src + (size_t)r * cols;
    const int t = threadIdx.x;
    float s = 0.f;
    const int nIter = cols >> 10;
    for (int i = 0; i < nIter; ++i) {
        const float4 v = *reinterpret_cast<const float4*>(row + (((i << 8) + t) << 2));
        s = fmaf(v.x, v.x, s); s = fmaf(v.y, v.y, s);
        s = fmaf(v.z, v.z, s); s = fmaf(v.w, v.w, s);
    }
    #pragma unroll
    for (int off = 32; off; off >>= 1) s += __shfl_down(s, off);
    __shared__ float red[4];
    if ((t & 63) == 0) red[t >> 6] = s;
    __syncthreads();
    if (t == 0) dst[r] = sqrtf(red[0] + red[1] + red[2] + red[3]);
}

__global__ __launch_bounds__(512, 2) void gemm_f16(
    const float* __restrict__ w,      // [32768][4096]
    const uint4* __restrict__ xf16,   // pre-converted x, fragment-linear
    const int*  __restrict__ age,
    float* __restrict__ cand,         // [512][128] block-row approx max
    float2* __restrict__ ent,         // candidate list
    unsigned* __restrict__ cnt)
{
    __shared__ uint4 Al[2][1024];     // A tile 256x32 f16, fragment-linear
    __shared__ uint4 Bl[2][1024];     // B tile 256x32 f16, 4 swizzled 16B slots/row
    __shared__ float ny_inv[256];
    __shared__ float comb[256][2];
    __shared__ float rowmaxs[256];
    __shared__ float2 lent[LCAP];
    __shared__ unsigned lcnt, gbase;

    const int tid = threadIdx.x;
    const int bx = blockIdx.x;        // BM half: 0,1
    const int b0 = bx << 8;
    const int y0 = blockIdx.y << 8;   // BN = 256

    // W staging: 2 threads/row; thread reads 64 contiguous bytes (16 f32)
    const int rB = tid >> 1, q = tid & 1;
    const int wi0 = (rB << 2) + (((q << 1)    ) ^ (rB & 3));
    const int wi1 = (rB << 2) + (((q << 1) | 1) ^ (rB & 3));
    const float* bP = w + (size_t)(y0 + rB) * 4096 + (q << 4);

    // MFMA decomposition: 8 waves = 4 wm x 2 wn, wave tile 64 rows x 128 cols
    const int lane = tid & 63, wave = tid >> 6;
    const int wm = wave >> 1, wn = wave & 1;
    const int kh = lane >> 5;
    const int iA = (wm << 8) + lane;  // + ks*128 + mi*64

    const int r0 = (wn << 7) + (lane & 31);
    const int r1 = r0 + 32, r2 = r0 + 64, r3 = r0 + 96;
    const int rb0 = r0 << 2, rb1 = r1 << 2, rb2 = r2 << 2, rb3 = r3 << 2;
    const int cc = lane & 3;          // r_j & 3 is the same for all j

    f32x16 am0n0 = (f32x16)0.f, am0n1 = (f32x16)0.f, am0n2 = (f32x16)0.f, am0n3 = (f32x16)0.f;
    f32x16 am1n0 = (f32x16)0.f, am1n1 = (f32x16)0.f, am1n2 = (f32x16)0.f, am1n3 = (f32x16)0.f;

    half8 a0, a1, fb0, fb1, fb2, fb3;
    float4 SAa, SAb, SAc, SAd;        // W reg set A (letter suffixes: pp-number safe)
    float4 SBa, SBb, SBc, SBd;        // W reg set B
    float nyacc = 0.f;

#define MF(a, b, c) __builtin_amdgcn_mfma_f32_32x32x16_f16(a, b, c, 0, 0, 0)
#define SBR __builtin_amdgcn_sched_barrier(0)
#define LG0 asm volatile("s_waitcnt lgkmcnt(0)" ::: "memory")

#define STAGEA(buf, tt) { \
    const uint4* g_ = xf16 + ((size_t)((((tt) << 1) | bx)) << 10); \
    GLDS(g_ + tid,       &Al[buf][tid]); \
    GLDS(g_ + 512 + tid, &Al[buf][512 + tid]); }

#define LOADW(S, tt) { const float* p_ = bP + ((tt) << 5); \
    S##a = *(const float4*)p_;       S##b = *(const float4*)(p_ + 4); \
    S##c = *(const float4*)(p_ + 8); S##d = *(const float4*)(p_ + 12); }

#define STOREB(buf, S) { uint4 u_; \
    u_.x = pk2h(S##a.x, S##a.y); u_.y = pk2h(S##a.z, S##a.w); \
    u_.z = pk2h(S##b.x, S##b.y); u_.w = pk2h(S##b.z, S##b.w); \
    Bl[buf][wi0] = u_; \
    u_.x = pk2h(S##c.x, S##c.y); u_.y = pk2h(S##c.z, S##c.w); \
    u_.z = pk2h(S##d.x, S##d.y); u_.w = pk2h(S##d.z, S##d.w); \
    Bl[buf][wi1] = u_; \
    nyacc = fmaf(S##a.x, S##a.x, nyacc); nyacc = fmaf(S##a.y, S##a.y, nyacc); \
    nyacc = fmaf(S##a.z, S##a.z, nyacc); nyacc = fmaf(S##a.w, S##a.w, nyacc); \
    nyacc = fmaf(S##b.x, S##b.x, nyacc); nyacc = fmaf(S##b.y, S##b.y, nyacc); \
    nyacc = fmaf(S##b.z, S##b.z, nyacc); nyacc = fmaf(S##b.w, S##b.w, nyacc); \
    nyacc = fmaf(S##c.x, S##c.x, nyacc); nyacc = fmaf(S##c.y, S##c.y, nyacc); \
    nyacc = fmaf(S##c.z, S##c.z, nyacc); nyacc = fmaf(S##c.w, S##c.w, nyacc); \
    nyacc = fmaf(S##d.x, S##d.x, nyacc); nyacc = fmaf(S##d.y, S##d.y, nyacc); \
    nyacc = fmaf(S##d.z, S##d.z, nyacc); nyacc = fmaf(S##d.w, S##d.w, nyacc); }

#define MFMA8 { __builtin_amdgcn_s_setprio(1); \
    am0n0 = MF(a0, fb0, am0n0); am0n1 = MF(a0, fb1, am0n1); \
    am1n0 = MF(a1, fb0, am1n0); am1n1 = MF(a1, fb1, am1n1); \
    am0n2 = MF(a0, fb2, am0n2); am0n3 = MF(a0, fb3, am0n3); \
    am1n2 = MF(a1, fb2, am1n2); am1n3 = MF(a1, fb3, am1n3); \
    __builtin_amdgcn_s_setprio(0); }

#define PHASE(cur, ks, EXTRA) { \
    a0  = *(const half8*)&Al[cur][iA + ((ks) << 7)]; \
    a1  = *(const half8*)&Al[cur][iA + ((ks) << 7) + 64]; \
    fb0 = *(const half8*)&Bl[cur][rb0 + ((((ks) << 1) | kh) ^ cc)]; \
    fb1 = *(const half8*)&Bl[cur][rb1 + ((((ks) << 1) | kh) ^ cc)]; \
    fb2 = *(const half8*)&Bl[cur][rb2 + ((((ks) << 1) | kh) ^ cc)]; \
    fb3 = *(const half8*)&Bl[cur][rb3 + ((((ks) << 1) | kh) ^ cc)]; \
    EXTRA \
    SBR; __builtin_amdgcn_s_barrier(); LG0; SBR; \
    MFMA8; \
    SBR; __builtin_amdgcn_s_barrier(); }

// One BK=32 tile = 2 phases.
// vmcnt ladder at tile t, phase 1 (steady state): outstanding =
//   [W(t+1) x4][GLDS(t+1) x2][W(t+2) x4]; compiler waits W(t+1) -> vmcnt(6);
//   manual vmcnt(4) drains GLDS(t+1) only -> W(t+2) stays in flight (T4).
#define TILE(cur, tt, SST, SLD, GA, GW) { \
    PHASE(cur, 0, if (GA) STAGEA((cur) ^ 1, (tt) + 1); \
                  if (GW) LOADW(SLD, (tt) + 2); ) \
    PHASE(cur, 1, if (GA) { STOREB((cur) ^ 1, SST); SBR; } \
                  if (GW) { asm volatile("s_waitcnt vmcnt(4)" ::: "memory"); } \
                  else if (GA) { asm volatile("s_waitcnt vmcnt(0)" ::: "memory"); } ) }

    // ---- prologue: tile 0 into buf0; W(1) left in SB ----
    STAGEA(0, 0);
    LOADW(SA, 0);
    STOREB(0, SA);    // compiler waits SA regs (drains GLDS(0) too, FIFO)
    LOADW(SB, 1);     // stays in flight across the barrier
    SBR; LG0; SBR;
    __builtin_amdgcn_s_barrier();

    for (int t = 0; t < 126; t += 2) {
        TILE(0, t,     SB, SA, 1, 1)   // store W(t+1)=SB, load W(t+2)->SA
        TILE(1, t + 1, SA, SB, 1, 1)
    }
    TILE(0, 126, SB, SA, 1, 0)
    TILE(1, 127, SA, SB, 0, 0)

    // ---- fused ||w_y|| (2 threads/row) ----
    float s_ = nyacc;
    s_ += __shfl_xor(s_, 1);
    if (q == 0) ny_inv[rB] = 1.0f / fmaxf(sqrtf(s_), 1e-12f);
    if (tid == 0) lcnt = 0u;
    __syncthreads();

    // ---- epilogue: gated scores, per-row max, candidate append ----
    // am{mi}n{ni}[v] = S[wm*64+mi*32+(v&3)+8*(v>>2)+4*kh][wn*128+ni*32+(lane&31)]
    const float scl0 = ny_inv[r0], scl1 = ny_inv[r1], scl2 = ny_inv[r2], scl3 = ny_inv[r3];
    const int act0 = age[y0 + r0] >= 1, act1 = age[y0 + r1] >= 1;
    const int act2 = age[y0 + r2] >= 1, act3 = age[y0 + r3] >= 1;
    const int yb0 = y0 + r0, yb1 = y0 + r1, yb2 = y0 + r2, yb3 = y0 + r3;
    const int rbase = (wm << 6) + (kh << 2);

#define ROWMAX(A0, A1, A2, A3, mibase) \
    _Pragma("unroll") for (int v = 0; v < 16; ++v) { \
        float bv = fmaxf( \
            fmaxf(act0 ? A0[v] * scl0 : 0.f, act1 ? A1[v] * scl1 : 0.f), \
            fmaxf(act2 ? A2[v] * scl2 : 0.f, act3 ? A3[v] * scl3 : 0.f)); \
        _Pragma("unroll") for (int off = 1; off < 32; off <<= 1) \
            bv = fmaxf(bv, __shfl_xor(bv, off)); \
        if ((lane & 31) == 0) comb[rbase + (mibase) + (v & 3) + ((v >> 2) << 3)][wn] = bv; \
    }
    ROWMAX(am0n0, am0n1, am0n2, am0n3, 0)
    ROWMAX(am1n0, am1n1, am1n2, am1n3, 32)
    __syncthreads();
    if (tid < 256) {
        const float rm = fmaxf(comb[tid][0], comb[tid][1]);
        cand[(size_t)(b0 + tid) * 128 + blockIdx.y] = rm;
        rowmaxs[tid] = rm;
    }
    __syncthreads();

#define APP1(ACv, actk, sclk, ybk, r_) { \
    if (actk) { const float sc_ = (ACv) * sclk; \
        if (sc_ >= rowmaxs[r_] - TAU) { \
            const unsigned ix_ = atomicAdd(&lcnt, 1u); \
            if (ix_ < LCAP) lent[ix_] = make_float2(sc_, \
                __uint_as_float(((unsigned)(b0 + r_) << 16) | (unsigned)(ybk))); } } }

#define APPEND(A0, A1, A2, A3, mibase) \
    _Pragma("unroll") for (int v = 0; v < 16; ++v) { \
        const int r_ = rbase + (mibase) + (v & 3) + ((v >> 2) << 3); \
        APP1(A0[v], act0, scl0, yb0, r_) \
        APP1(A1[v], act1, scl1, yb1, r_) \
        APP1(A2[v], act2, scl2, yb2, r_) \
        APP1(A3[v], act3, scl3, yb3, r_) }
    APPEND(am0n0, am0n1, am0n2, am0n3, 0)
    APPEND(am1n0, am1n1, am1n2, am1n3, 32)
    __syncthreads();
    if (tid == 0) gbase = atomicAdd(cnt, min(lcnt, LCAP));
    __syncthreads();
    const unsigned nL = min(lcnt, LCAP);
    for (unsigned i = tid; i < nL; i += 512) {
        const unsigned gi = gbase + i;
        if (gi < CAP) ent[gi] = lent[i];
    }
#undef MF
#undef SBR
#undef LG0
#undef STAGEA
#undef LOADW
#undef STOREB
#undef MFMA8
#undef PHASE
#undef TILE
#undef ROWMAX
#undef APP1
#undef APPEND
}

__global__ __launch_bounds__(128) void reduce_gmax(const float* __restrict__ cand,
                                                   float* __restrict__ gmax) {
    const int b = blockIdx.x, t = threadIdx.x;
    float m = cand[(size_t)b * 128 + t];
    #pragma unroll
    for (int off = 32; off; off >>= 1) m = fmaxf(m, __shfl_xor(m, off));
    __shared__ float sm[2];
    if ((t & 63) == 0) sm[t >> 6] = m;
    __syncthreads();
    if (t == 0) gmax[b] = fmaxf(sm[0], sm[1]);
}

// exact f32 rescore; ballot-compacted scan, wave-per-survivor dot product
__global__ __launch_bounds__(256) void rescore(
    const float* __restrict__ x, const float* __restrict__ w,
    const float* __restrict__ gmax, const float2* __restrict__ ent,
    const unsigned* __restrict__ cnt, ull* __restrict__ win)
{
    const unsigned n = min(*cnt, CAP);
    const int lane = threadIdx.x & 63;
    const unsigned wid = (blockIdx.x * 256 + threadIdx.x) >> 6;
    const unsigned nwv = (gridDim.x * 256) >> 6;
    for (unsigned base = wid << 6; base < n; base += (nwv << 6)) {
        const unsigned e = base + (unsigned)lane;
        unsigned by = 0u;
        bool ok = false;
        if (e < n) {
            const float2 en = ent[e];
            by = __float_as_uint(en.y);
            ok = en.x >= gmax[by >> 16] - TAU;
        }
        ull m = __ballot(ok);
        while (m) {
            const int s = __ffsll((ull)m) - 1;
            m &= m - 1;
            const unsigned bys = __shfl(by, s);
            const unsigned b = bys >> 16, y = bys & 0xffffu;
            const float4* xr = (const float4*)(x + (size_t)b * 4096);
            const float4* wr = (const float4*)(w + (size_t)y * 4096);
            float sdot = 0.f, nn = 0.f;
            #pragma unroll
            for (int k = 0; k < 16; ++k) {
                const float4 xv = xr[(k << 6) + lane];
                const float4 wv = wr[(k << 6) + lane];
                sdot = fmaf(xv.x, wv.x, sdot); sdot = fmaf(xv.y, wv.y, sdot);
                sdot = fmaf(xv.z, wv.z, sdot); sdot = fmaf(xv.w, wv.w, sdot);
                nn = fmaf(wv.x, wv.x, nn); nn = fmaf(wv.y, wv.y, nn);
                nn = fmaf(wv.z, wv.z, nn); nn = fmaf(wv.w, wv.w, nn);
            }
            #pragma unroll
            for (int off = 32; off; off >>= 1) {
                sdot += __shfl_xor(sdot, off);
                nn   += __shfl_xor(nn, off);
            }
            if (lane == 0) {
                const float sc = sdot / fmaxf(sqrtf(nn), 1e-12f);
                atomicMax(win + b, packkey(sc, y));
            }
        }
    }
}

__global__ __launch_bounds__(256) void gather_out(const float* __restrict__ y2z,
                                                  const float* __restrict__ nz,
                                                  const ull* __restrict__ win,
                                                  float* __restrict__ out) {
    const int g = blockIdx.x * 256 + threadIdx.x;
    if (g >= 512 * 1000) return;
    const int b = g / 1000, z = g - b * 1000;
    const unsigned lo = (unsigned)(win[b] & 0xffffffffull);
    const int yw = (int)(0x7FFFFFFFu - lo);
    out[g] = y2z[(size_t)z * 32768 + yw] / fmaxf(nz[z], 1e-12f);
}

extern "C" void kernel_launch(void* const* d_in, const int* in_sizes, int n_in,
                              void* d_out, int out_size, void* d_ws, size_t ws_size,
                              hipStream_t stream) {
    const float* x     = (const float*)d_in[0];
    const float* x2y_w = (const float*)d_in[2];
    const float* y2z_w = (const float*)d_in[3];
    const int*   y_age = (const int*)d_in[4];
    float* out = (float*)d_out;

    // ws layout (bytes)
    char* p = (char*)d_ws;
    float*    cand = (float*)p;                       // 512*128*4 = 262144
    float*    nz   = (float*)(p + 262144);            // 4096
    float*    gmax = (float*)(p + 266240);            // 2048
    ull*      win  = (ull*)(p + 268288);              // 4096
    unsigned* cnt  = (unsigned*)(p + 272384);         // 64
    uint4*    xf16 = (uint4*)(p + 272448);            // 4 MB
    float2*   ent  = (float2*)(p + 4466752);          // CAP*8

    init_ctrl<<<1, 512, 0, stream>>>(y_age, win, cnt);
    convert_x<<<512, 512, 0, stream>>>(x, xf16);
    row_norms<<<1000, 256, 0, stream>>>(y2z_w, nz, 32768);

    gemm_f16<<<dim3(2, 128), 512, 0, stream>>>(x2y_w, xf16, y_age, cand, ent, cnt);
    reduce_gmax<<<512, 128, 0, stream>>>(cand, gmax);
    rescore<<<256, 256, 0, stream>>>(x, x2y_w, gmax, ent, cnt, win);
    gather_out<<<(512 * 1000 + 255) / 256, 256, 0, stream>>>(y2z_w, nz, win, out);
}